// Round 10
// baseline (77.169 us; speedup 1.0000x reference)
//
#include <hip/hip_runtime.h>

// ---------------------------------------------------------------------------
// SpeciesSpecificNetworkBranch — window-in-LDS compaction + bf16 MFMA, v2.
//
// R9 post-mortem: window phases were barrier-serialized (4 barriers + thread-0
// serial scan) and each block grid-strided ~4 windows serially -> latency-
// bound with all pipes idle. R10: ONE 512-row window per block (1954 blocks,
// CP keeps fresh blocks flowing -> cross-window overlap), all-thread redundant
// scan (no thread-0 phase), 2 barriers/window, first-tile weight loads issued
// before barrier 2. Padding waste 24%->13.5%.
//
// Structure: X staged coalesced -> bf16 LDS tile (XOR-swizzled 16B slots);
// ballot-rank compaction into per-species 32-row tiles; each wave runs
// single-species tiles (species wave-uniform -> scalar weight addressing).
// Weights BN-folded (+0.92) & frag-packed by k_pre, read per-tile from global
// (42KB table, L2-hot). Out-stores direct scattered (within 64KB window).
//
// math: z1 = W1^T x + b1
//       z2 = W2f^T relu(z1) + Wsc^T x + bias2f     (W2f = diag(A1) W2)
//       out = relu(Wshf_s^T relu(z2) + bshf_s)     (0.92 pre-folded)
// C'[feature][sample] via mfma_f32_32x32x16_bf16; sample lane-local, so
// relu + v_cvt_pk_bf16_f32 + permlane32_swap chains layers in registers.
// ---------------------------------------------------------------------------

#define EPSBN 1e-5f
#define TPB 256
#define WIN 512           // rows per window (= one block)

typedef __attribute__((ext_vector_type(8))) short bf16x8;
typedef __attribute__((ext_vector_type(16))) float f32x16;
typedef __attribute__((ext_vector_type(4))) unsigned u32x4;

union FU { unsigned u[4]; bf16x8 v; u32x4 q; };

static __device__ __forceinline__ unsigned pkbf(float lo, float hi) {
    unsigned r;
    asm("v_cvt_pk_bf16_f32 %0, %1, %2" : "=v"(r) : "v"(lo), "v"(hi));
    return r;
}

// --- pre-pack: fold BN (and 0.92) into weights/biases, pack MFMA A-frags ---
// wfrag uints [s][m][c][64][4]  (m: 0=W1 1=Wsc 2=W2f 3=Wshf), 10240 words
// bconst floats [s][q][hi][16]  (q: 0=b1 1=bias2f 2=bshf), 480 floats
__global__ void k_pre(unsigned* __restrict__ wfrag, float* __restrict__ bconst,
                      const float* __restrict__ W1, const float* __restrict__ b1,
                      const float* __restrict__ g1, const float* __restrict__ be1,
                      const float* __restrict__ mu1, const float* __restrict__ va1,
                      const float* __restrict__ W2, const float* __restrict__ b2,
                      const float* __restrict__ g2, const float* __restrict__ be2,
                      const float* __restrict__ mu2, const float* __restrict__ va2,
                      const float* __restrict__ Wsc, const float* __restrict__ bsc,
                      const float* __restrict__ Wsh, const float* __restrict__ bsh) {
    if (blockIdx.x < 40) {
        const int i = blockIdx.x * 256 + threadIdx.x;   // wfrag word index
        const int p = i & 3, l = (i >> 2) & 63, c = (i >> 8) & 1;
        const int m = (i >> 9) & 3, s = i >> 11;
        const int ln = l & 31, hi = l >> 5;
        const int k0 = c * 16 + hi * 8 + 2 * p;
        float lo, hv;
        if (m == 0)      { lo = W1[s*1024 + k0*32 + ln];  hv = W1[s*1024 + (k0+1)*32 + ln]; }
        else if (m == 1) { lo = Wsc[s*1024 + k0*32 + ln]; hv = Wsc[s*1024 + (k0+1)*32 + ln]; }
        else if (m == 2) {
            float A0 = g1[s*32+k0]   * rsqrtf(va1[s*32+k0]   + EPSBN);
            float A1 = g1[s*32+k0+1] * rsqrtf(va1[s*32+k0+1] + EPSBN);
            lo = A0 * W2[s*1024 + k0*32 + ln]; hv = A1 * W2[s*1024 + (k0+1)*32 + ln];
        } else {
            float A0 = 0.92f * g2[s*32+k0]   * rsqrtf(va2[s*32+k0]   + EPSBN);
            float A1 = 0.92f * g2[s*32+k0+1] * rsqrtf(va2[s*32+k0+1] + EPSBN);
            lo = A0 * Wsh[k0*32 + ln]; hv = A1 * Wsh[(k0+1)*32 + ln];
        }
        wfrag[i] = pkbf(lo, hv);
    } else {
        for (int i = threadIdx.x; i < 480; i += 256) {
            const int reg = i & 15, hi = (i >> 4) & 1, t = i >> 5;
            const int q = t % 3, s = t / 3;
            const int r = (reg & 3) + 8 * (reg >> 2) + 4 * hi;
            float v;
            if (q == 0) v = b1[s*32 + r];
            else if (q == 1) {
                v = b2[s*32 + r] + bsc[s*32 + r];
                for (int k = 0; k < 32; ++k) {
                    float A = g1[s*32+k] * rsqrtf(va1[s*32+k] + EPSBN);
                    float C = be1[s*32+k] - mu1[s*32+k] * A;
                    v = fmaf(C, W2[s*1024 + k*32 + r], v);
                }
            } else {
                v = bsh[r];
                for (int k = 0; k < 32; ++k) {
                    float A = g2[s*32+k] * rsqrtf(va2[s*32+k] + EPSBN);
                    float C = be2[s*32+k] - mu2[s*32+k] * A;
                    v = fmaf(C, Wsh[k*32 + r], v);
                }
                v *= 0.92f;
            }
            bconst[i] = v;
        }
    }
}

// relu-only transition: C' acc -> next layer's B-frags (cvt_pk + permlane32).
static __device__ __forceinline__ void reluT(const f32x16& c, bf16x8& f0, bf16x8& f1) {
    unsigned p[8];
    #pragma unroll
    for (int i = 0; i < 8; ++i)
        p[i] = pkbf(fmaxf(c[2 * i], 0.f), fmaxf(c[2 * i + 1], 0.f));
    auto s0 = __builtin_amdgcn_permlane32_swap(p[0], p[2], false, false);
    auto s1 = __builtin_amdgcn_permlane32_swap(p[1], p[3], false, false);
    auto s2 = __builtin_amdgcn_permlane32_swap(p[4], p[6], false, false);
    auto s3 = __builtin_amdgcn_permlane32_swap(p[5], p[7], false, false);
    FU u0, u1;
    u0.u[0] = s0[0]; u0.u[1] = s1[0]; u0.u[2] = s0[1]; u0.u[3] = s1[1];
    u1.u[0] = s2[0]; u1.u[1] = s3[0]; u1.u[2] = s2[1]; u1.u[3] = s3[1];
    f0 = u0.v; f1 = u1.v;
}

static __device__ __forceinline__ void store_row(float* __restrict__ op, const f32x16& a3) {
    #pragma unroll
    for (int q = 0; q < 4; ++q) {
        float4 v;
        v.x = fmaxf(a3[4 * q + 0], 0.f);
        v.y = fmaxf(a3[4 * q + 1], 0.f);
        v.z = fmaxf(a3[4 * q + 2], 0.f);
        v.w = fmaxf(a3[4 * q + 3], 0.f);
        *(float4*)(op + q * 8) = v;
    }
}

__global__ __launch_bounds__(TPB, 4) void k_main(
    const float* __restrict__ X, const int* __restrict__ sid,
    const unsigned* __restrict__ wfrag, const float* __restrict__ bconst,
    float* __restrict__ out, int B) {
    // bf16 window tile [512 rows][4 slots x 16B], XOR-swizzled slots
    __shared__ __align__(16) unsigned char xb[32768];
    __shared__ float clds[480];
    __shared__ int idxl[672];       // 512 + 5*31 padded slots, rounded up
    __shared__ int wq[2][4][5];     // [iter][wave][species]

    const int tid = threadIdx.x;
    const int l   = tid & 63;
    const int ln  = l & 31;
    const int hi  = l >> 5;
    const int wav = tid >> 6;
    const unsigned long long ltmask = (1ull << l) - 1ull;
    const int wbase = blockIdx.x * WIN;

    for (int i = tid; i < 480; i += TPB) clds[i] = bconst[i];

    // ---- stage X coalesced -> bf16 LDS (swizzled). 8 iters x 8 floats/t.
    const long fmax = (long)B * 32 - 8;
    #pragma unroll
    for (int k = 0; k < 8; ++k) {
        long fo = (long)wbase * 32 + k * 2048 + tid * 8;
        if (fo > fmax) fo = fmax;
        float4 xa = *(const float4*)(X + fo);
        float4 xc = *(const float4*)(X + fo + 4);
        FU u;
        u.u[0] = pkbf(xa.x, xa.y); u.u[1] = pkbf(xa.z, xa.w);
        u.u[2] = pkbf(xc.x, xc.y); u.u[3] = pkbf(xc.z, xc.w);
        const int row  = k * 64 + (tid >> 2);
        const int slot = (tid & 3) ^ (row & 3);
        *(u32x4*)(xb + row * 64 + slot * 16) = u.q;
    }

    // ---- species ballots: per-(iter,wave) counts + in-wave rank
    int sv[2], prank[2];
    #pragma unroll
    for (int it = 0; it < 2; ++it) {
        const int row = wbase + it * TPB + tid;
        sv[it] = (row < B) ? sid[row] : -1;
        prank[it] = 0;
        #pragma unroll
        for (int sp = 0; sp < 5; ++sp) {
            unsigned long long m = __ballot(sv[it] == sp);
            if (l == 0) wq[it][wav][sp] = (int)__popcll(m);
            if (sv[it] == sp) prank[it] = (int)__popcll(m & ltmask);
        }
    }
    // sentinel-fill idxl (positions independent of counts; before barrier 1)
    for (int i = tid; i < 672; i += TPB) idxl[i] = -1;
    __syncthreads();   // barrier 1: xb, wq, clds, sentinels visible

    // ---- all-thread redundant scan: per-species tile bases (no thread-0 phase)
    int tb[6];
    {
        int t = 0;
        #pragma unroll
        for (int sp = 0; sp < 5; ++sp) {
            tb[sp] = t;
            int c = 0;
            #pragma unroll
            for (int it = 0; it < 2; ++it)
                #pragma unroll
                for (int w2 = 0; w2 < 4; ++w2) c += wq[it][w2][sp];
            t += (c + 31) >> 5;
        }
        tb[5] = t;
    }

    // ---- rank-write local row index into species segment
    #pragma unroll
    for (int it = 0; it < 2; ++it) {
        const int s = sv[it];
        if (s >= 0) {
            int off = tb[s] * 32 + prank[it];
            for (int t2 = 0; t2 < it; ++t2)
                #pragma unroll
                for (int w2 = 0; w2 < 4; ++w2) off += wq[t2][w2][s];
            for (int w2 = 0; w2 < wav; ++w2) off += wq[it][w2][s];
            idxl[off] = it * TPB + tid;
        }
    }

    // ---- first tile's species + weight loads issued BEFORE barrier 2
    const int ntl = tb[5];
    int t = wav;
    int csp = 0;
    FU w00, w01, w10, w11, w20, w21, w30, w31;
    if (t < ntl) {
        #pragma unroll
        for (int k = 1; k < 5; ++k) csp += (t >= tb[k]) ? 1 : 0;
        csp = __builtin_amdgcn_readfirstlane(csp);
        const unsigned* wp = wfrag + csp * 2048;
        w00.q = *(const u32x4*)(wp + (0 * 64 + l) * 4);
        w01.q = *(const u32x4*)(wp + (1 * 64 + l) * 4);
        w10.q = *(const u32x4*)(wp + (2 * 64 + l) * 4);
        w11.q = *(const u32x4*)(wp + (3 * 64 + l) * 4);
        w20.q = *(const u32x4*)(wp + (4 * 64 + l) * 4);
        w21.q = *(const u32x4*)(wp + (5 * 64 + l) * 4);
        w30.q = *(const u32x4*)(wp + (6 * 64 + l) * 4);
        w31.q = *(const u32x4*)(wp + (7 * 64 + l) * 4);
    }
    __syncthreads();   // barrier 2: idxl visible

    // ---- phase B: single-species tiles; frags from LDS, weights global
    for (; t < ntl; t += 4) {
        const int lid = idxl[t * 32 + ln];
        const int r = lid < 0 ? 0 : lid;

        const float* cp = clds + csp * 96;
        f32x16 a1 = *(const f32x16*)(cp + hi * 16);
        f32x16 a2 = *(const f32x16*)(cp + 32 + hi * 16);

        const int rs = r & 3;
        const bf16x8 b0 = *(const bf16x8*)(xb + r * 64 + ((hi ^ rs) << 4));
        const bf16x8 b1 = *(const bf16x8*)(xb + r * 64 + (((2 + hi) ^ rs) << 4));

        a1 = __builtin_amdgcn_mfma_f32_32x32x16_bf16(w00.v, b0, a1, 0, 0, 0);
        a2 = __builtin_amdgcn_mfma_f32_32x32x16_bf16(w10.v, b0, a2, 0, 0, 0);
        a1 = __builtin_amdgcn_mfma_f32_32x32x16_bf16(w01.v, b1, a1, 0, 0, 0);
        a2 = __builtin_amdgcn_mfma_f32_32x32x16_bf16(w11.v, b1, a2, 0, 0, 0);

        bf16x8 h0, h1;
        reluT(a1, h0, h1);
        a2 = __builtin_amdgcn_mfma_f32_32x32x16_bf16(w20.v, h0, a2, 0, 0, 0);
        a2 = __builtin_amdgcn_mfma_f32_32x32x16_bf16(w21.v, h1, a2, 0, 0, 0);

        bf16x8 g0, g1;
        reluT(a2, g0, g1);
        f32x16 a3 = *(const f32x16*)(cp + 64 + hi * 16);
        a3 = __builtin_amdgcn_mfma_f32_32x32x16_bf16(w30.v, g0, a3, 0, 0, 0);
        a3 = __builtin_amdgcn_mfma_f32_32x32x16_bf16(w31.v, g1, a3, 0, 0, 0);

        // prefetch next tile's species + weights (independent of this store)
        const int tn = t + 4;
        if (tn < ntl) {
            int nsp = 0;
            #pragma unroll
            for (int k = 1; k < 5; ++k) nsp += (tn >= tb[k]) ? 1 : 0;
            nsp = __builtin_amdgcn_readfirstlane(nsp);
            csp = nsp;
            const unsigned* wp = wfrag + nsp * 2048;
            w00.q = *(const u32x4*)(wp + (0 * 64 + l) * 4);
            w01.q = *(const u32x4*)(wp + (1 * 64 + l) * 4);
            w10.q = *(const u32x4*)(wp + (2 * 64 + l) * 4);
            w11.q = *(const u32x4*)(wp + (3 * 64 + l) * 4);
            w20.q = *(const u32x4*)(wp + (4 * 64 + l) * 4);
            w21.q = *(const u32x4*)(wp + (5 * 64 + l) * 4);
            w30.q = *(const u32x4*)(wp + (6 * 64 + l) * 4);
            w31.q = *(const u32x4*)(wp + (7 * 64 + l) * 4);
        }

        if (lid >= 0) store_row(out + (long)(wbase + lid) * 32 + hi * 4, a3);
    }
}

extern "C" void kernel_launch(void* const* d_in, const int* in_sizes, int n_in,
                              void* d_out, int out_size, void* d_ws, size_t ws_size,
                              hipStream_t stream) {
    const float* X   = (const float*)d_in[0];
    const int*   sid = (const int*)d_in[1];
    const float* W1  = (const float*)d_in[2];
    const float* b1  = (const float*)d_in[3];
    const float* g1  = (const float*)d_in[4];
    const float* be1 = (const float*)d_in[5];
    const float* mu1 = (const float*)d_in[6];
    const float* va1 = (const float*)d_in[7];
    const float* W2  = (const float*)d_in[8];
    const float* b2  = (const float*)d_in[9];
    const float* g2  = (const float*)d_in[10];
    const float* be2 = (const float*)d_in[11];
    const float* mu2 = (const float*)d_in[12];
    const float* va2 = (const float*)d_in[13];
    const float* Wsc = (const float*)d_in[14];
    const float* bsc = (const float*)d_in[15];
    const float* Wsh = (const float*)d_in[16];
    const float* bsh = (const float*)d_in[17];
    float* out = (float*)d_out;
    const int B = in_sizes[1];

    unsigned* wfrag = (unsigned*)d_ws;          // 10240 u32
    float* bconst   = (float*)(wfrag + 10240);  // 480 f32

    k_pre<<<41, 256, 0, stream>>>(wfrag, bconst,
                                  W1, b1, g1, be1, mu1, va1,
                                  W2, b2, g2, be2, mu2, va2,
                                  Wsc, bsc, Wsh, bsh);

    const int nwin = (B + WIN - 1) / WIN;
    k_main<<<nwin, TPB, 0, stream>>>(X, sid, wfrag, bconst, out, B);
}

// Round 11
// 63.657 us; speedup vs baseline: 1.2123x; 1.2123x over previous
//
#include <hip/hip_runtime.h>

// ---------------------------------------------------------------------------
// SpeciesSpecificNetworkBranch — window compaction + bf16 MFMA + coalesced
// writeback + async-staged window pipeline (R11).
//
// R4-R10 lesson: all variants hit ~95us profiled with every pipe idle. Two
// shared defects: (1) scattered 16B out-stores (each instr touches 64 cache
// lines); (2) __syncthreads drains vmcnt(0), serializing each window's HBM
// stage latency with compute.
// R11: (1) phase B writes results into a 32KB f32 LDS out-buffer by natural
// local row (XOR-swizzled); a flush phase streams it to global fully
// coalesced -> ALL global traffic unit-stride. (2) next window's X loads are
// issued into registers before barrier 2 (T14) and the 3 per-window barriers
// are raw lgkmcnt(0)+s_barrier (no vmcnt drain) so HBM latency hides under
// scan+phaseB+flush.
//
// Hazards (3 barriers/window): xb write(w+1)@top vs read(w)@phaseB  — b3.
// wq write(w+1) vs read(w)@scan — b2,b3. idxl sentinel(w+1) vs read(w) — b3.
// ob write(w+1)@phaseB vs read(w)@flush — b1',b2'. All >=1 barrier apart.
//
// math: z1 = W1^T x + b1
//       z2 = W2f^T relu(z1) + Wsc^T x + bias2f     (W2f = diag(A1) W2)
//       out = relu(Wshf_s^T relu(z2) + bshf_s)     (0.92 pre-folded)
// C'[feature][sample] via mfma_f32_32x32x16_bf16; sample lane-local;
// relu + v_cvt_pk_bf16_f32 + permlane32_swap chains layers in registers.
// ---------------------------------------------------------------------------

#define EPSBN 1e-5f
#define TPB 256
#define WIN 256
#define NBLKMAX 768    // 3 blocks/CU (LDS ~52.8KB)

typedef __attribute__((ext_vector_type(8))) short bf16x8;
typedef __attribute__((ext_vector_type(16))) float f32x16;
typedef __attribute__((ext_vector_type(4))) unsigned u32x4;

union FU { unsigned u[4]; bf16x8 v; u32x4 q; };

static __device__ __forceinline__ unsigned pkbf(float lo, float hi) {
    unsigned r;
    asm("v_cvt_pk_bf16_f32 %0, %1, %2" : "=v"(r) : "v"(lo), "v"(hi));
    return r;
}

// raw barrier: LDS-visibility only (no vmcnt drain -> global prefetch stays
// in flight across it). All producers this barrier orders are LDS writes.
static __device__ __forceinline__ void ldsbar() {
    asm volatile("s_waitcnt lgkmcnt(0)" ::: "memory");
    __builtin_amdgcn_s_barrier();
}

// --- pre-pack: fold BN (and 0.92) into weights/biases, pack MFMA A-frags ---
// wfrag uints [s][m][c][64][4]  (m: 0=W1 1=Wsc 2=W2f 3=Wshf), 10240 words
// bconst floats [s][q][hi][16]  (q: 0=b1 1=bias2f 2=bshf), 480 floats
__global__ void k_pre(unsigned* __restrict__ wfrag, float* __restrict__ bconst,
                      const float* __restrict__ W1, const float* __restrict__ b1,
                      const float* __restrict__ g1, const float* __restrict__ be1,
                      const float* __restrict__ mu1, const float* __restrict__ va1,
                      const float* __restrict__ W2, const float* __restrict__ b2,
                      const float* __restrict__ g2, const float* __restrict__ be2,
                      const float* __restrict__ mu2, const float* __restrict__ va2,
                      const float* __restrict__ Wsc, const float* __restrict__ bsc,
                      const float* __restrict__ Wsh, const float* __restrict__ bsh) {
    if (blockIdx.x < 40) {
        const int i = blockIdx.x * 256 + threadIdx.x;   // wfrag word index
        const int p = i & 3, l = (i >> 2) & 63, c = (i >> 8) & 1;
        const int m = (i >> 9) & 3, s = i >> 11;
        const int ln = l & 31, hi = l >> 5;
        const int k0 = c * 16 + hi * 8 + 2 * p;
        float lo, hv;
        if (m == 0)      { lo = W1[s*1024 + k0*32 + ln];  hv = W1[s*1024 + (k0+1)*32 + ln]; }
        else if (m == 1) { lo = Wsc[s*1024 + k0*32 + ln]; hv = Wsc[s*1024 + (k0+1)*32 + ln]; }
        else if (m == 2) {
            float A0 = g1[s*32+k0]   * rsqrtf(va1[s*32+k0]   + EPSBN);
            float A1 = g1[s*32+k0+1] * rsqrtf(va1[s*32+k0+1] + EPSBN);
            lo = A0 * W2[s*1024 + k0*32 + ln]; hv = A1 * W2[s*1024 + (k0+1)*32 + ln];
        } else {
            float A0 = 0.92f * g2[s*32+k0]   * rsqrtf(va2[s*32+k0]   + EPSBN);
            float A1 = 0.92f * g2[s*32+k0+1] * rsqrtf(va2[s*32+k0+1] + EPSBN);
            lo = A0 * Wsh[k0*32 + ln]; hv = A1 * Wsh[(k0+1)*32 + ln];
        }
        wfrag[i] = pkbf(lo, hv);
    } else {
        for (int i = threadIdx.x; i < 480; i += 256) {
            const int reg = i & 15, hi = (i >> 4) & 1, t = i >> 5;
            const int q = t % 3, s = t / 3;
            const int r = (reg & 3) + 8 * (reg >> 2) + 4 * hi;
            float v;
            if (q == 0) v = b1[s*32 + r];
            else if (q == 1) {
                v = b2[s*32 + r] + bsc[s*32 + r];
                for (int k = 0; k < 32; ++k) {
                    float A = g1[s*32+k] * rsqrtf(va1[s*32+k] + EPSBN);
                    float C = be1[s*32+k] - mu1[s*32+k] * A;
                    v = fmaf(C, W2[s*1024 + k*32 + r], v);
                }
            } else {
                v = bsh[r];
                for (int k = 0; k < 32; ++k) {
                    float A = g2[s*32+k] * rsqrtf(va2[s*32+k] + EPSBN);
                    float C = be2[s*32+k] - mu2[s*32+k] * A;
                    v = fmaf(C, Wsh[k*32 + r], v);
                }
                v *= 0.92f;
            }
            bconst[i] = v;
        }
    }
}

// relu-only transition: C' acc -> next layer's B-frags (cvt_pk + permlane32).
static __device__ __forceinline__ void reluT(const f32x16& c, bf16x8& f0, bf16x8& f1) {
    unsigned p[8];
    #pragma unroll
    for (int i = 0; i < 8; ++i)
        p[i] = pkbf(fmaxf(c[2 * i], 0.f), fmaxf(c[2 * i + 1], 0.f));
    auto s0 = __builtin_amdgcn_permlane32_swap(p[0], p[2], false, false);
    auto s1 = __builtin_amdgcn_permlane32_swap(p[1], p[3], false, false);
    auto s2 = __builtin_amdgcn_permlane32_swap(p[4], p[6], false, false);
    auto s3 = __builtin_amdgcn_permlane32_swap(p[5], p[7], false, false);
    FU u0, u1;
    u0.u[0] = s0[0]; u0.u[1] = s1[0]; u0.u[2] = s0[1]; u0.u[3] = s1[1];
    u1.u[0] = s2[0]; u1.u[1] = s3[0]; u1.u[2] = s2[1]; u1.u[3] = s3[1];
    f0 = u0.v; f1 = u1.v;
}

__global__ __launch_bounds__(TPB, 3) void k_main(
    const float* __restrict__ X, const int* __restrict__ sid,
    const unsigned* __restrict__ wfrag, const float* __restrict__ bconst,
    float* __restrict__ out, int B) {
    __shared__ __align__(16) unsigned char xb[16384];  // bf16 [256 rows][4x16B], swizzled
    __shared__ __align__(16) float ob[8192];           // f32 out-stage [256 rows][32], swizzled
    __shared__ float clds[480];
    __shared__ int idxl[416];
    __shared__ int wq[4][5];

    const int tid = threadIdx.x;
    const int l   = tid & 63;
    const int ln  = l & 31;
    const int hi  = l >> 5;
    const int wav = tid >> 6;
    const unsigned long long ltmask = (1ull << l) - 1ull;

    for (int i = tid; i < 480; i += TPB) clds[i] = bconst[i];

    const int nwin = (B + WIN - 1) / WIN;
    const long fmaxo = (long)B * 32 - 8;

    // prefetched window data (registers)
    float4 pa[4], pb[4];
    int svp = -1;

    // prologue: load first window
    int w0 = blockIdx.x;
    if (w0 < nwin) {
        #pragma unroll
        for (int k = 0; k < 4; ++k) {
            long fo = (long)w0 * (WIN * 32) + k * 2048 + tid * 8;
            if (fo > fmaxo) fo = fmaxo;
            pa[k] = *(const float4*)(X + fo);
            pb[k] = *(const float4*)(X + fo + 4);
        }
        int row = w0 * WIN + tid;
        svp = (row < B) ? sid[row < B ? row : B - 1] : -1;
    }

    for (int w = w0; w < nwin; w += gridDim.x) {
        const int wbase = w * WIN;
        const int rows = min(WIN, B - wbase);

        // ---- stage: cvt prefetched regs -> bf16 LDS tile (swizzled slots)
        #pragma unroll
        for (int k = 0; k < 4; ++k) {
            FU u;
            u.u[0] = pkbf(pa[k].x, pa[k].y); u.u[1] = pkbf(pa[k].z, pa[k].w);
            u.u[2] = pkbf(pb[k].x, pb[k].y); u.u[3] = pkbf(pb[k].z, pb[k].w);
            const int row  = k * 64 + (tid >> 2);
            const int slot = (tid & 3) ^ (row & 3);
            *(u32x4*)(xb + row * 64 + slot * 16) = u.q;
        }

        // ---- ballots: per-wave counts + in-wave rank; sentinel idxl
        const int s = svp;
        int prank = 0;
        #pragma unroll
        for (int sp = 0; sp < 5; ++sp) {
            unsigned long long m = __ballot(s == sp);
            if (l == 0) wq[wav][sp] = (int)__popcll(m);
            if (s == sp) prank = (int)__popcll(m & ltmask);
        }
        for (int i = tid; i < 416; i += TPB) idxl[i] = -1;
        ldsbar();   // b1: xb, wq, sentinels visible

        // ---- all-thread scan: per-species tile bases
        int tb[6];
        {
            int t = 0;
            #pragma unroll
            for (int sp = 0; sp < 5; ++sp) {
                tb[sp] = t;
                int c = wq[0][sp] + wq[1][sp] + wq[2][sp] + wq[3][sp];
                t += (c + 31) >> 5;
            }
            tb[5] = t;
        }
        // ---- rank-write local row into species segment
        if (s >= 0) {
            int off = tb[s] * 32 + prank;
            for (int w2 = 0; w2 < wav; ++w2) off += wq[w2][s];
            idxl[off] = tid;
        }

        // ---- issue NEXT window's global loads (consumed after b3+loop; no
        //      vmcnt drain at the raw barriers -> latency hides under phase B)
        const int wn = w + gridDim.x;
        if (wn < nwin) {
            #pragma unroll
            for (int k = 0; k < 4; ++k) {
                long fo = (long)wn * (WIN * 32) + k * 2048 + tid * 8;
                if (fo > fmaxo) fo = fmaxo;
                pa[k] = *(const float4*)(X + fo);
                pb[k] = *(const float4*)(X + fo + 4);
            }
            int row = wn * WIN + tid;
            svp = (row < B) ? sid[row] : -1;
        }
        ldsbar();   // b2: idxl visible

        // ---- phase B: single-species tiles; frags from LDS; results -> ob
        const int ntl = tb[5];
        for (int t = wav; t < ntl; t += 4) {
            int csp = 0;
            #pragma unroll
            for (int k = 1; k < 5; ++k) csp += (t >= tb[k]) ? 1 : 0;
            csp = __builtin_amdgcn_readfirstlane(csp);
            const int lid = idxl[t * 32 + ln];
            const int r = lid < 0 ? 0 : lid;

            const unsigned* wp = wfrag + csp * 2048;   // coalesced, L2-hot
            FU w00, w01, w10, w11, w20, w21, w30, w31;
            w00.q = *(const u32x4*)(wp + (0 * 64 + l) * 4);
            w01.q = *(const u32x4*)(wp + (1 * 64 + l) * 4);
            w10.q = *(const u32x4*)(wp + (2 * 64 + l) * 4);
            w11.q = *(const u32x4*)(wp + (3 * 64 + l) * 4);
            w20.q = *(const u32x4*)(wp + (4 * 64 + l) * 4);
            w21.q = *(const u32x4*)(wp + (5 * 64 + l) * 4);
            w30.q = *(const u32x4*)(wp + (6 * 64 + l) * 4);
            w31.q = *(const u32x4*)(wp + (7 * 64 + l) * 4);

            const float* cp = clds + csp * 96;
            f32x16 a1 = *(const f32x16*)(cp + hi * 16);
            f32x16 a2 = *(const f32x16*)(cp + 32 + hi * 16);

            const int rs = r & 3;
            const bf16x8 b0 = *(const bf16x8*)(xb + r * 64 + ((hi ^ rs) << 4));
            const bf16x8 b1 = *(const bf16x8*)(xb + r * 64 + (((2 + hi) ^ rs) << 4));

            a1 = __builtin_amdgcn_mfma_f32_32x32x16_bf16(w00.v, b0, a1, 0, 0, 0);
            a2 = __builtin_amdgcn_mfma_f32_32x32x16_bf16(w10.v, b0, a2, 0, 0, 0);
            a1 = __builtin_amdgcn_mfma_f32_32x32x16_bf16(w01.v, b1, a1, 0, 0, 0);
            a2 = __builtin_amdgcn_mfma_f32_32x32x16_bf16(w11.v, b1, a2, 0, 0, 0);

            bf16x8 h0, h1;
            reluT(a1, h0, h1);
            a2 = __builtin_amdgcn_mfma_f32_32x32x16_bf16(w20.v, h0, a2, 0, 0, 0);
            a2 = __builtin_amdgcn_mfma_f32_32x32x16_bf16(w21.v, h1, a2, 0, 0, 0);

            bf16x8 g0, g1;
            reluT(a2, g0, g1);
            f32x16 a3 = *(const f32x16*)(cp + 64 + hi * 16);
            a3 = __builtin_amdgcn_mfma_f32_32x32x16_bf16(w30.v, g0, a3, 0, 0, 0);
            a3 = __builtin_amdgcn_mfma_f32_32x32x16_bf16(w31.v, g1, a3, 0, 0, 0);

            if (lid >= 0) {
                // write relu'd result into LDS out-stage at natural row lid,
                // piece (hi,q) -> float offset (hi*4+q*8) ^ ((lid&7)<<2)
                #pragma unroll
                for (int q = 0; q < 4; ++q) {
                    float4 v;
                    v.x = fmaxf(a3[4 * q + 0], 0.f);
                    v.y = fmaxf(a3[4 * q + 1], 0.f);
                    v.z = fmaxf(a3[4 * q + 2], 0.f);
                    v.w = fmaxf(a3[4 * q + 3], 0.f);
                    const int fs = (hi * 4 + q * 8) ^ ((lid & 7) << 2);
                    *(float4*)(ob + lid * 32 + fs) = v;
                }
            }
        }
        ldsbar();   // b3: ob visible

        // ---- flush: LDS out-stage -> global, fully coalesced 16B pieces
        #pragma unroll
        for (int k = 0; k < 8; ++k) {
            const int p = k * TPB + tid;
            const int row = p >> 3, sl = p & 7;
            if (row < rows) {
                const int fs = (sl * 4) ^ ((row & 7) << 2);
                float4 v = *(const float4*)(ob + row * 32 + fs);
                *(float4*)(out + (long)(wbase + row) * 32 + sl * 4) = v;
            }
        }
    }
}

extern "C" void kernel_launch(void* const* d_in, const int* in_sizes, int n_in,
                              void* d_out, int out_size, void* d_ws, size_t ws_size,
                              hipStream_t stream) {
    const float* X   = (const float*)d_in[0];
    const int*   sid = (const int*)d_in[1];
    const float* W1  = (const float*)d_in[2];
    const float* b1  = (const float*)d_in[3];
    const float* g1  = (const float*)d_in[4];
    const float* be1 = (const float*)d_in[5];
    const float* mu1 = (const float*)d_in[6];
    const float* va1 = (const float*)d_in[7];
    const float* W2  = (const float*)d_in[8];
    const float* b2  = (const float*)d_in[9];
    const float* g2  = (const float*)d_in[10];
    const float* be2 = (const float*)d_in[11];
    const float* mu2 = (const float*)d_in[12];
    const float* va2 = (const float*)d_in[13];
    const float* Wsc = (const float*)d_in[14];
    const float* bsc = (const float*)d_in[15];
    const float* Wsh = (const float*)d_in[16];
    const float* bsh = (const float*)d_in[17];
    float* out = (float*)d_out;
    const int B = in_sizes[1];

    unsigned* wfrag = (unsigned*)d_ws;          // 10240 u32
    float* bconst   = (float*)(wfrag + 10240);  // 480 f32

    k_pre<<<41, 256, 0, stream>>>(wfrag, bconst,
                                  W1, b1, g1, be1, mu1, va1,
                                  W2, b2, g2, be2, mu2, va2,
                                  Wsc, bsc, Wsh, bsh);

    const int nwin = (B + WIN - 1) / WIN;
    const int nblocks = min(NBLKMAX, nwin);
    k_main<<<nblocks, TPB, 0, stream>>>(X, sid, wfrag, bconst, out, B);
}